// Round 3
// baseline (5525.503 us; speedup 1.0000x reference)
//
#include <hip/hip_runtime.h>
#include <hip/hip_bf16.h>
#include <stdint.h>

typedef unsigned short u16;
typedef __attribute__((ext_vector_type(8))) __bf16 bf16x8;
typedef __attribute__((ext_vector_type(4))) float  f32x4;

__device__ __forceinline__ float bf2f(u16 v) {
    union { unsigned int u; float f; } x; x.u = ((unsigned int)v) << 16; return x.f;
}
__device__ __forceinline__ u16 f2bf(float f) {
    union { float f; unsigned int u; } x; x.f = f;
    unsigned int u = x.u;
    unsigned int lsb = (u >> 16) & 1u;
    u += 0x7fffu + lsb;                      // round-to-nearest-even
    return (u16)(u >> 16);
}

#define GLDS16(gp, lp)                                                         \
    __builtin_amdgcn_global_load_lds(                                          \
        (const __attribute__((address_space(1))) void*)(gp),                   \
        (__attribute__((address_space(3))) void*)(lp), 16, 0, 0)

// ---------------------------------------------------------------------------
// fp32 -> bf16 conversion, 4 elements/thread
// ---------------------------------------------------------------------------
__global__ __launch_bounds__(256) void cvt_kernel(const float* __restrict__ src,
                                                  u16* __restrict__ dst, int n4)
{
    int gid = blockIdx.x * 256 + threadIdx.x;
    if (gid < n4) {
        float4 v = ((const float4*)src)[gid];
        ushort4 o;
        o.x = f2bf(v.x); o.y = f2bf(v.y); o.z = f2bf(v.z); o.w = f2bf(v.w);
        ((ushort4*)dst)[gid] = o;
    }
}

// ---------------------------------------------------------------------------
// merged per-layer weight conversion
// ---------------------------------------------------------------------------
__global__ __launch_bounds__(256) void cvt4_kernel(
    const float* __restrict__ s0, const float* __restrict__ s1,
    const float* __restrict__ s2, const float* __restrict__ s3,
    u16* __restrict__ d0, u16* __restrict__ d1,
    u16* __restrict__ d2, u16* __restrict__ d3)
{
    int gid = blockIdx.x * 256 + threadIdx.x;
    const float* s; u16* d; int idx;
    if (gid < 786432)                { s = s0; d = d0; idx = gid; }
    else if (gid < 1048576)          { s = s1; d = d1; idx = gid - 786432; }
    else if (gid < 1572864)          { s = s2; d = d2; idx = gid - 1048576; }
    else                             { s = s3; d = d3; idx = gid - 1572864; }
    float4 v = ((const float4*)s)[idx];
    ushort4 o;
    o.x = f2bf(v.x); o.y = f2bf(v.y); o.z = f2bf(v.z); o.w = f2bf(v.w);
    ((ushort4*)d)[idx] = o;
}

// ---------------------------------------------------------------------------
// Deep-pipelined MFMA GEMM — m201-geometry 256x256 8-phase template.
//   C = act(scale * A @ B^T + bias) + residual
//   A: [M,K] bf16 rm (lda), B: [N,K] bf16 rm (ldb), C: bf16/fp32 (ldc)
// BM=BN=256, BK=64, 512 threads = 8 waves (2M x 4N), per-wave 128x64
// (acc 8x4 frags), 4 phases/K-tile x 16 MFMA. LDS 128 KiB (2-tile dbuf).
// Staging: groups of 2 global_load_lds (half-tile of A or B).
//   steady state per tile t: phase0 issues A1(t+1); phase3 issues
//   A0,B0,B1(t+2); one counted vmcnt(6) per tile (invariant: entering
//   tile t exactly {A0,B0,B1}(t+1) outstanding).
// Swizzle: 16B slot ^= (row&7) on BOTH stage-source and ds_read.
// Requires: M%256==0, N%256==0, K%64==0, K>=128, grid (N/256, M/256),
// nwg % 8 == 0.
// ---------------------------------------------------------------------------
__global__ __launch_bounds__(512, 2) void gemm8p(
    const u16* __restrict__ A, const u16* __restrict__ B,
    const float* __restrict__ bias, const float* __restrict__ res,
    void* __restrict__ Cout, int c_fp32,
    int K, int lda, int ldb, int ldc, int ldres, float scale, int act)
{
    __shared__ __align__(16) u16 As[2][256 * 64];   // 64 KB
    __shared__ __align__(16) u16 Bs[2][256 * 64];   // 64 KB

    int nt = K >> 6;

    // XCD-aware block swizzle (nwg % 8 == 0 at all call sites)
    int gx  = gridDim.x;
    int nwg = gx * gridDim.y;
    int bid = blockIdx.y * gx + blockIdx.x;
    int cpx = nwg >> 3;
    int swz = (bid & 7) * cpx + (bid >> 3);
    int m0 = (swz / gx) << 8;
    int n0 = (swz % gx) << 8;

    int t = threadIdx.x;
    int w = t >> 6, l = t & 63;
    int wm = w >> 2, wn = w & 3;          // 2M x 4N wave grid
    int lg = l >> 4, lr = l & 15, r7 = lr & 7;

    // ---- staging source (pre-swizzled global, linear LDS dest) ----
    // chunk c (16B) covers row = c>>3, slot = c&7 of a [rows][64k] tile.
    int tr = t >> 3, ts = t & 7;
    int tsw = ts ^ (tr & 7);              // pre-swizzled 16B slot
    const u16* Ag = A + (long long)(m0 + tr) * lda + (tsw << 3);
    const u16* Bg = B + (long long)(n0 + tr) * ldb + (tsw << 3);
    long long a64 = (long long)lda << 6, a128 = (long long)lda << 7;
    long long b64 = (long long)ldb << 6, b128 = (long long)ldb << 7;

    u16* AsW = &As[0][0] + (w << 9);
    u16* BsW = &Bs[0][0] + (w << 9);

    // group = 2 loads/thread = 128 rows (half-tile) of A or B
#define SG_A0(tt) { u16* d_ = AsW + (((tt) & 1) << 14);                        \
        const u16* g_ = Ag + ((long long)(tt) << 6);                           \
        GLDS16(g_, d_); GLDS16(g_ + a64, d_ + 4096); }
#define SG_A1(tt) { u16* d_ = AsW + (((tt) & 1) << 14) + 8192;                 \
        const u16* g_ = Ag + ((long long)(tt) << 6) + a128;                    \
        GLDS16(g_, d_); GLDS16(g_ + a64, d_ + 4096); }
#define SG_B0(tt) { u16* d_ = BsW + (((tt) & 1) << 14);                        \
        const u16* g_ = Bg + ((long long)(tt) << 6);                           \
        GLDS16(g_, d_); GLDS16(g_ + b64, d_ + 4096); }
#define SG_B1(tt) { u16* d_ = BsW + (((tt) & 1) << 14) + 8192;                 \
        const u16* g_ = Bg + ((long long)(tt) << 6) + b128;                    \
        GLDS16(g_, d_); GLDS16(g_ + b64, d_ + 4096); }

    // ---- read-side offsets (u16 units; row stride 64) ----
    // A-frag row = wm*128 + mh*64 + i*16 + lr ; slot = (ks*4+lg)^r7
    int aoff0 = ((wm << 7) + lr) * 64 + ((lg ^ r7) << 3);          // ks=0
    int aoff1 = ((wm << 7) + lr) * 64 + (((4 | lg) ^ r7) << 3);    // ks=1
    int boff0 = ((wn << 6) + lr) * 64 + ((lg ^ r7) << 3);
    int boff1 = ((wn << 6) + lr) * 64 + (((4 | lg) ^ r7) << 3);

    f32x4 acc[8][4];
#pragma unroll
    for (int m = 0; m < 8; m++)
#pragma unroll
        for (int n = 0; n < 4; n++)
            acc[m][n] = (f32x4){0.f, 0.f, 0.f, 0.f};

    // ---- prologue: tile0 all 4 groups, tile1 {A0,B0,B1}; wait tile0 ----
    SG_A0(0); SG_A1(0); SG_B0(0); SG_B1(0);
    SG_A0(1); SG_B0(1); SG_B1(1);
    asm volatile("s_waitcnt vmcnt(6)" ::: "memory");
    __builtin_amdgcn_s_barrier();
    __builtin_amdgcn_sched_barrier(0);

    for (int tt = 0; tt < nt; ++tt) {
        const u16* Ab = &As[0][0] + ((tt & 1) << 14);
        const u16* Bb = &Bs[0][0] + ((tt & 1) << 14);
        bf16x8 a[4], bb0[4], bb1[4];

        // ===== phase 0: A[mh0,ks0] + B[ks0]; stage A1(t+1) =====
#pragma unroll
        for (int i = 0; i < 4; i++) a[i]   = *(const bf16x8*)(Ab + aoff0 + i * 1024);
#pragma unroll
        for (int n = 0; n < 4; n++) bb0[n] = *(const bf16x8*)(Bb + boff0 + n * 1024);
        if (tt + 1 < nt) SG_A1(tt + 1);
        __builtin_amdgcn_sched_barrier(0);
        __builtin_amdgcn_s_barrier();
        asm volatile("s_waitcnt lgkmcnt(0)" ::: "memory");
        __builtin_amdgcn_sched_barrier(0);
        __builtin_amdgcn_s_setprio(1);
#pragma unroll
        for (int n = 0; n < 4; n++)
#pragma unroll
            for (int i = 0; i < 4; i++)
                acc[i][n] = __builtin_amdgcn_mfma_f32_16x16x32_bf16(a[i], bb0[n], acc[i][n], 0, 0, 0);
        __builtin_amdgcn_s_setprio(0);
        __builtin_amdgcn_s_barrier();
        __builtin_amdgcn_sched_barrier(0);

        // ===== phase 1: A[mh1,ks0] =====
#pragma unroll
        for (int i = 0; i < 4; i++) a[i] = *(const bf16x8*)(Ab + aoff0 + 4096 + i * 1024);
        __builtin_amdgcn_sched_barrier(0);
        __builtin_amdgcn_s_barrier();
        asm volatile("s_waitcnt lgkmcnt(0)" ::: "memory");
        __builtin_amdgcn_sched_barrier(0);
        __builtin_amdgcn_s_setprio(1);
#pragma unroll
        for (int n = 0; n < 4; n++)
#pragma unroll
            for (int i = 0; i < 4; i++)
                acc[4 + i][n] = __builtin_amdgcn_mfma_f32_16x16x32_bf16(a[i], bb0[n], acc[4 + i][n], 0, 0, 0);
        __builtin_amdgcn_s_setprio(0);
        __builtin_amdgcn_s_barrier();
        __builtin_amdgcn_sched_barrier(0);

        // ===== phase 2: A[mh0,ks1] + B[ks1] =====
#pragma unroll
        for (int i = 0; i < 4; i++) a[i]   = *(const bf16x8*)(Ab + aoff1 + i * 1024);
#pragma unroll
        for (int n = 0; n < 4; n++) bb1[n] = *(const bf16x8*)(Bb + boff1 + n * 1024);
        __builtin_amdgcn_sched_barrier(0);
        __builtin_amdgcn_s_barrier();
        asm volatile("s_waitcnt lgkmcnt(0)" ::: "memory");
        __builtin_amdgcn_sched_barrier(0);
        __builtin_amdgcn_s_setprio(1);
#pragma unroll
        for (int n = 0; n < 4; n++)
#pragma unroll
            for (int i = 0; i < 4; i++)
                acc[i][n] = __builtin_amdgcn_mfma_f32_16x16x32_bf16(a[i], bb1[n], acc[i][n], 0, 0, 0);
        __builtin_amdgcn_s_setprio(0);
        __builtin_amdgcn_s_barrier();
        __builtin_amdgcn_sched_barrier(0);

        // ===== phase 3: A[mh1,ks1]; stage A0,B0,B1(t+2); counted vmcnt =====
#pragma unroll
        for (int i = 0; i < 4; i++) a[i] = *(const bf16x8*)(Ab + aoff1 + 4096 + i * 1024);
        if (tt + 2 < nt) { SG_A0(tt + 2); SG_B0(tt + 2); SG_B1(tt + 2); }
        __builtin_amdgcn_sched_barrier(0);
        __builtin_amdgcn_s_barrier();
        asm volatile("s_waitcnt lgkmcnt(0)" ::: "memory");
        __builtin_amdgcn_sched_barrier(0);
        __builtin_amdgcn_s_setprio(1);
#pragma unroll
        for (int n = 0; n < 4; n++)
#pragma unroll
            for (int i = 0; i < 4; i++)
                acc[4 + i][n] = __builtin_amdgcn_mfma_f32_16x16x32_bf16(a[i], bb1[n], acc[4 + i][n], 0, 0, 0);
        __builtin_amdgcn_s_setprio(0);
        if (tt + 2 < nt)      { asm volatile("s_waitcnt vmcnt(6)" ::: "memory"); }
        else if (tt + 1 < nt) { asm volatile("s_waitcnt vmcnt(0)" ::: "memory"); }
        __builtin_amdgcn_s_barrier();
        __builtin_amdgcn_sched_barrier(0);
    }
#undef SG_A0
#undef SG_A1
#undef SG_B0
#undef SG_B1

    // ---- epilogue: C/D layout col = lane&15, row = lg*4 + r ----
    int rq = lg << 2;
#pragma unroll
    for (int n = 0; n < 4; n++) {
        int col = n0 + (wn << 6) + (n << 4) + lr;
        float bvv = bias ? bias[col] : 0.f;
#pragma unroll
        for (int m = 0; m < 8; m++) {
#pragma unroll
            for (int r = 0; r < 4; r++) {
                int row = m0 + (wm << 7) + (m << 4) + rq + r;
                float v = acc[m][n][r] * scale + bvv;
                if (act) v = 0.5f * v * (1.f + erff(v * 0.70710678118654752f));
                if (res) v += res[(long long)row * ldres + col];
                long long idx = (long long)row * ldc + col;
                if (c_fp32) ((float*)Cout)[idx] = v;
                else        ((u16*)Cout)[idx]  = f2bf(v);
            }
        }
    }
}

// ---------------------------------------------------------------------------
// Fused flash attention (unchanged).
// ---------------------------------------------------------------------------
#define ASCALE 0.08838834764831845f

__global__ __launch_bounds__(256) void attn_kernel(
    const u16* __restrict__ qkv, const u16* __restrict__ vt,
    u16* __restrict__ out)
{
    __shared__ __align__(16) u16 Ks[64 * 128];   // [key][k], slot-swizzled
    __shared__ __align__(16) u16 Vs[128 * 64];   // [d][key], slot-swizzled
    __shared__ __align__(16) u16 Ps[4][32 * 72]; // per-wave P, pad 64->72

    int bh = blockIdx.y; int b = bh >> 3, hd = bh & 7;
    int q0 = blockIdx.x << 7;
    int t = threadIdx.x, w = t >> 6, l = t & 63;
    int lg = l >> 4, lr = l & 15;

    const u16* qp = qkv + ((long long)(b * 1024 + q0 + (w << 5) + lr)) * 3072
                        + hd * 128 + (lg << 3);
    bf16x8 qf[2][4];
#pragma unroll
    for (int rb = 0; rb < 2; rb++)
#pragma unroll
        for (int kf = 0; kf < 4; kf++)
            qf[rb][kf] = *(const bf16x8*)(qp + rb * 16 * 3072 + (kf << 5));

    const u16* kg = qkv + ((long long)(b * 1024)) * 3072 + 1024 + hd * 128;
    const u16* vg = vt + (long long)bh * 131072;
    u16* Pw = &Ps[w][0];

    f32x4 oa[2][8];
#pragma unroll
    for (int rb = 0; rb < 2; rb++)
#pragma unroll
        for (int db = 0; db < 8; db++)
            oa[rb][db] = (f32x4){0.f, 0.f, 0.f, 0.f};
    float m_run[2][4], l_run[2][4];
#pragma unroll
    for (int rb = 0; rb < 2; rb++)
#pragma unroll
        for (int r = 0; r < 4; r++) { m_run[rb][r] = -1e30f; l_run[rb][r] = 0.f; }

    for (int kv0 = 0; kv0 < 1024; kv0 += 64) {
#pragma unroll
        for (int i = 0; i < 4; i++) {
            int ck   = (((w << 2) + i) << 6) + l;
            int krow = ck >> 4;
            int kslot = (ck & 15) ^ (krow & 7);
            GLDS16(kg + (long long)(kv0 + krow) * 3072 + (kslot << 3),
                   Ks + (((w << 2) + i) << 9));
            int vd   = ck >> 3;
            int vslot = (ck & 7) ^ (vd & 7);
            GLDS16(vg + (long long)vd * 1024 + kv0 + (vslot << 3),
                   Vs + (((w << 2) + i) << 9));
        }
        __syncthreads();

        f32x4 s[2][4];
#pragma unroll
        for (int kb = 0; kb < 4; kb++) {
            s[0][kb] = (f32x4){0.f, 0.f, 0.f, 0.f};
            s[1][kb] = (f32x4){0.f, 0.f, 0.f, 0.f};
        }
#pragma unroll
        for (int kf = 0; kf < 4; kf++)
#pragma unroll
            for (int kb = 0; kb < 4; kb++) {
                bf16x8 bk = *(const bf16x8*)
                    &Ks[(((kb << 4) + lr) << 7) + (((((kf << 2) + lg)) ^ (lr & 7)) << 3)];
                s[0][kb] = __builtin_amdgcn_mfma_f32_16x16x32_bf16(qf[0][kf], bk, s[0][kb], 0, 0, 0);
                s[1][kb] = __builtin_amdgcn_mfma_f32_16x16x32_bf16(qf[1][kf], bk, s[1][kb], 0, 0, 0);
            }

#pragma unroll
        for (int rb = 0; rb < 2; rb++) {
            float mx[4], al[4], rs[4];
#pragma unroll
            for (int r = 0; r < 4; r++)
                mx[r] = fmaxf(fmaxf(s[rb][0][r], s[rb][1][r]),
                              fmaxf(s[rb][2][r], s[rb][3][r]));
#pragma unroll
            for (int mask = 1; mask < 16; mask <<= 1)
#pragma unroll
                for (int r = 0; r < 4; r++)
                    mx[r] = fmaxf(mx[r], __shfl_xor(mx[r], mask));
#pragma unroll
            for (int r = 0; r < 4; r++) {
                float mn = fmaxf(m_run[rb][r], mx[r] * ASCALE);
                al[r] = __expf(m_run[rb][r] - mn);
                m_run[rb][r] = mn;
                rs[r] = 0.f;
            }
#pragma unroll
            for (int kb = 0; kb < 4; kb++)
#pragma unroll
                for (int r = 0; r < 4; r++) {
                    float p = __expf(s[rb][kb][r] * ASCALE - m_run[rb][r]);
                    rs[r] += p;
                    Pw[((rb << 4) + (lg << 2) + r) * 72 + (kb << 4) + lr] = f2bf(p);
                }
#pragma unroll
            for (int mask = 1; mask < 16; mask <<= 1)
#pragma unroll
                for (int r = 0; r < 4; r++)
                    rs[r] += __shfl_xor(rs[r], mask);
#pragma unroll
            for (int r = 0; r < 4; r++)
                l_run[rb][r] = l_run[rb][r] * al[r] + rs[r];
#pragma unroll
            for (int db = 0; db < 8; db++)
#pragma unroll
                for (int r = 0; r < 4; r++)
                    oa[rb][db][r] *= al[r];
        }

#pragma unroll
        for (int ks = 0; ks < 2; ks++) {
            bf16x8 pa0 = *(const bf16x8*)&Pw[lr * 72 + (ks << 5) + (lg << 3)];
            bf16x8 pa1 = *(const bf16x8*)&Pw[(16 + lr) * 72 + (ks << 5) + (lg << 3)];
#pragma unroll
            for (int db = 0; db < 8; db++) {
                bf16x8 vf = *(const bf16x8*)
                    &Vs[(((db << 4) + lr) << 6) + ((((ks << 2) + lg) ^ (lr & 7)) << 3)];
                oa[0][db] = __builtin_amdgcn_mfma_f32_16x16x32_bf16(pa0, vf, oa[0][db], 0, 0, 0);
                oa[1][db] = __builtin_amdgcn_mfma_f32_16x16x32_bf16(pa1, vf, oa[1][db], 0, 0, 0);
            }
        }
        __syncthreads();
    }

    long long obase = ((long long)(b * 1024 + q0 + (w << 5)) << 10) + hd * 128;
#pragma unroll
    for (int rb = 0; rb < 2; rb++) {
        float il[4];
#pragma unroll
        for (int r = 0; r < 4; r++) il[r] = 1.f / l_run[rb][r];
#pragma unroll
        for (int db = 0; db < 8; db++)
#pragma unroll
            for (int r = 0; r < 4; r++)
                out[obase + (long long)((rb << 4) + (lg << 2) + r) * 1024
                          + (db << 4) + lr] = f2bf(oa[rb][db][r] * il[r]);
    }
}

// ---------------------------------------------------------------------------
// patch gather
// ---------------------------------------------------------------------------
__global__ __launch_bounds__(256) void patches_kernel(const float* __restrict__ x,
                                                      u16* __restrict__ p)
{
    int gid = blockIdx.x * 256 + threadIdx.x;
    int c = gid & 255, tk = gid >> 8;
    int b = tk >> 10, n = tk & 1023;
    int ph = n >> 5, pw = n & 31;
    int i = c >> 4, j = c & 15;
    p[gid] = f2bf(x[((long long)b << 18) + (long long)(ph * 16 + i) * 512 + pw * 16 + j]);
}

// ---------------------------------------------------------------------------
// positional encoding add
// ---------------------------------------------------------------------------
__global__ __launch_bounds__(256) void posenc_kernel(float* __restrict__ tok)
{
    int gid = blockIdx.x * 256 + threadIdx.x;
    int d = gid & 1023;
    int n = (gid >> 10) & 1023;
    int j = d >> 1;
    float ang = (float)n * exp2f(-13.287712379549449f * (float)j * (1.0f / 256.0f));
    float pe = (d & 1) ? cosf(ang) : sinf(ang);
    tok[gid] += pe;
}

// ---------------------------------------------------------------------------
// LayerNorm over last dim (1024): fp32 in, bf16 out
// ---------------------------------------------------------------------------
__global__ __launch_bounds__(256) void ln_kernel(const float* __restrict__ x,
                                                 const float* __restrict__ g,
                                                 const float* __restrict__ b,
                                                 u16* __restrict__ y)
{
    int row = blockIdx.x, t = threadIdx.x;
    const float* xr = x + (long long)row * 1024;
    float v[4]; float s = 0.f, ss = 0.f;
#pragma unroll
    for (int i = 0; i < 4; i++) { v[i] = xr[i * 256 + t]; s += v[i]; ss += v[i] * v[i]; }
    __shared__ float rs[256], rss[256];
    rs[t] = s; rss[t] = ss; __syncthreads();
    for (int o = 128; o > 0; o >>= 1) {
        if (t < o) { rs[t] += rs[t + o]; rss[t] += rss[t + o]; }
        __syncthreads();
    }
    float mean = rs[0] * (1.f / 1024.f);
    float var  = rss[0] * (1.f / 1024.f) - mean * mean;
    float rstd = rsqrtf(var + 1e-5f);
    u16* yr = y + (long long)row * 1024;
#pragma unroll
    for (int i = 0; i < 4; i++) {
        int d = i * 256 + t;
        yr[d] = f2bf((v[i] - mean) * rstd * g[d] + b[d]);
    }
}

// ---------------------------------------------------------------------------
// V transpose: qkv[token][2048 + head*128 + d] -> vt[bh][d][n]
// ---------------------------------------------------------------------------
__global__ __launch_bounds__(256) void vt_kernel(const u16* __restrict__ qkv,
                                                 u16* __restrict__ vt)
{
    int bh   = blockIdx.x >> 4;
    int tile = blockIdx.x & 15;
    int b = bh >> 3, hd = bh & 7;
    int t = threadIdx.x;
    __shared__ u16 tl[64][130];
    int nk0 = tile * 64;
    int dcol = t & 127, r0 = t >> 7;
    const u16* src = qkv + ((long long)(b * 1024 + nk0)) * 3072 + 2048 + hd * 128 + dcol;
#pragma unroll
    for (int r = 0; r < 32; r++) {
        int nk = r0 + r * 2;
        tl[nk][dcol] = src[(long long)nk * 3072];
    }
    __syncthreads();
    u16* dst = vt + ((long long)bh * 128) * 1024 + nk0;
#pragma unroll
    for (int r = 0; r < 32; r++) {
        int flat = r * 256 + t;
        int d = flat >> 6, nk = flat & 63;
        dst[(long long)d * 1024 + nk] = tl[nk][d];
    }
}

// ---------------------------------------------------------------------------
// reconstruction
// ---------------------------------------------------------------------------
__global__ __launch_bounds__(256) void recon_kernel(const float* __restrict__ tok,
                                                    float* __restrict__ out)
{
    int gid = blockIdx.x * 256 + threadIdx.x;
    int b  = gid >> 20;
    int y  = (gid >> 10) & 1023;
    int xx = gid & 1023;
    int p1 = y & 1,  hh = y >> 1,  a  = hh >> 4, i = hh & 15;
    int p2 = xx & 1, wv = xx >> 1, bb = wv >> 4, j = wv & 15;
    int n = a * 32 + bb;
    int d = ((i * 16 + j) << 2) + (p1 << 1) + p2;
    out[gid] = tok[((long long)(b * 1024 + n) << 10) + d];
}

// ---------------------------------------------------------------------------
extern "C" void kernel_launch(void* const* d_in, const int* in_sizes, int n_in,
                              void* d_out, int out_size, void* d_ws, size_t ws_size,
                              hipStream_t stream)
{
    (void)in_sizes; (void)n_in; (void)out_size; (void)ws_size;
    const float* x      = (const float*)d_in[0];
    const float* conv_w = (const float*)d_in[1];
    const float* conv_b = (const float*)d_in[2];
    const float* ln1_g  = (const float*)d_in[3];
    const float* ln1_b  = (const float*)d_in[4];
    const float* qkv_w  = (const float*)d_in[5];
    const float* qkv_b  = (const float*)d_in[6];
    const float* proj_w = (const float*)d_in[7];
    const float* proj_b = (const float*)d_in[8];
    const float* ln2_g  = (const float*)d_in[9];
    const float* ln2_b  = (const float*)d_in[10];
    const float* fc1_w  = (const float*)d_in[11];
    const float* fc1_b  = (const float*)d_in[12];
    const float* fc2_w  = (const float*)d_in[13];
    const float* fc2_b  = (const float*)d_in[14];

    char* ws = (char*)d_ws;
    float* tokf  = (float*)ws;                         // 33,554,432 B
    u16* h       = (u16*)(ws + 33554432);              // 16,777,216
    u16* qkvb    = (u16*)(ws + 50331648);              // 50,331,648
    u16* vt      = (u16*)(ws + 100663296);             // 16,777,216
    u16* attnout = (u16*)(ws + 117440512);             // 16,777,216
    u16* mid     = (u16*)(ws + 134217728);             // 33,554,432
    u16* patches = (u16*)(ws + 167772160);             //  4,194,304
    u16* convw   = (u16*)(ws + 171966464);             //    524,288
    u16* wqkv    = (u16*)(ws + 172490752);             //  6,291,456
    u16* wproj   = (u16*)(ws + 178782208);             //  2,097,152
    u16* wfc1    = (u16*)(ws + 180879360);             //  4,194,304
    u16* wfc2    = (u16*)(ws + 185073664);             //  4,194,304

    dim3 blk(256);
    dim3 blk512(512);

    // ---- patch embed ----
    patches_kernel<<<dim3(8192), blk, 0, stream>>>(x, patches);
    cvt_kernel<<<dim3(256), blk, 0, stream>>>(conv_w, convw, 65536);
    gemm8p<<<dim3(4, 32), blk512, 0, stream>>>(
        patches, convw, conv_b, (const float*)nullptr, (void*)tokf, 1,
        256, 256, 256, 1024, 0, 1.0f, 0);
    posenc_kernel<<<dim3(32768), blk, 0, stream>>>(tokf);

    // ---- transformer layers ----
    for (int L = 0; L < 12; L++) {
        cvt4_kernel<<<dim3(8192), blk, 0, stream>>>(
            qkv_w + (long long)L * 3145728, proj_w + (long long)L * 1048576,
            fc1_w + (long long)L * 2097152, fc2_w + (long long)L * 2097152,
            wqkv, wproj, wfc1, wfc2);

        ln_kernel<<<dim3(8192), blk, 0, stream>>>(
            tokf, ln1_g + L * 1024, ln1_b + L * 1024, h);

        gemm8p<<<dim3(12, 32), blk512, 0, stream>>>(
            h, wqkv, qkv_b + L * 3072, (const float*)nullptr, (void*)qkvb, 0,
            1024, 1024, 1024, 3072, 0, 1.0f, 0);

        vt_kernel<<<dim3(1024), blk, 0, stream>>>(qkvb, vt);

        attn_kernel<<<dim3(8, 64, 1), blk, 0, stream>>>(qkvb, vt, attnout);

        gemm8p<<<dim3(4, 32), blk512, 0, stream>>>(
            attnout, wproj, proj_b + L * 1024, tokf, (void*)tokf, 1,
            1024, 1024, 1024, 1024, 1024, 1.0f, 0);

        ln_kernel<<<dim3(8192), blk, 0, stream>>>(
            tokf, ln2_g + L * 1024, ln2_b + L * 1024, h);

        gemm8p<<<dim3(8, 32), blk512, 0, stream>>>(
            h, wfc1, fc1_b + L * 2048, (const float*)nullptr, (void*)mid, 0,
            1024, 1024, 1024, 2048, 0, 1.0f, 1);

        gemm8p<<<dim3(4, 32), blk512, 0, stream>>>(
            mid, wfc2, fc2_b + L * 1024, tokf, (void*)tokf, 1,
            2048, 2048, 2048, 1024, 1024, 1.0f, 0);
    }

    // ---- reconstruction ----
    recon_kernel<<<dim3(32768), blk, 0, stream>>>(tokf, (float*)d_out);
}

// Round 4
// 4450.672 us; speedup vs baseline: 1.2415x; 1.2415x over previous
//
#include <hip/hip_runtime.h>
#include <hip/hip_bf16.h>
#include <stdint.h>

typedef unsigned short u16;
typedef __attribute__((ext_vector_type(8))) __bf16 bf16x8;
typedef __attribute__((ext_vector_type(4))) float  f32x4;

__device__ __forceinline__ float bf2f(u16 v) {
    union { unsigned int u; float f; } x; x.u = ((unsigned int)v) << 16; return x.f;
}
__device__ __forceinline__ u16 f2bf(float f) {
    union { float f; unsigned int u; } x; x.f = f;
    unsigned int u = x.u;
    unsigned int lsb = (u >> 16) & 1u;
    u += 0x7fffu + lsb;                      // round-to-nearest-even
    return (u16)(u >> 16);
}

#define GLDS16(gp, lp)                                                         \
    __builtin_amdgcn_global_load_lds(                                          \
        (const __attribute__((address_space(1))) void*)(gp),                   \
        (__attribute__((address_space(3))) void*)(lp), 16, 0, 0)

// ---------------------------------------------------------------------------
// fp32 -> bf16 conversion, 4 elements/thread
// ---------------------------------------------------------------------------
__global__ __launch_bounds__(256) void cvt_kernel(const float* __restrict__ src,
                                                  u16* __restrict__ dst, int n4)
{
    int gid = blockIdx.x * 256 + threadIdx.x;
    if (gid < n4) {
        float4 v = ((const float4*)src)[gid];
        ushort4 o;
        o.x = f2bf(v.x); o.y = f2bf(v.y); o.z = f2bf(v.z); o.w = f2bf(v.w);
        ((ushort4*)dst)[gid] = o;
    }
}

// ---------------------------------------------------------------------------
// merged per-layer weight conversion
// ---------------------------------------------------------------------------
__global__ __launch_bounds__(256) void cvt4_kernel(
    const float* __restrict__ s0, const float* __restrict__ s1,
    const float* __restrict__ s2, const float* __restrict__ s3,
    u16* __restrict__ d0, u16* __restrict__ d1,
    u16* __restrict__ d2, u16* __restrict__ d3)
{
    int gid = blockIdx.x * 256 + threadIdx.x;
    const float* s; u16* d; int idx;
    if (gid < 786432)                { s = s0; d = d0; idx = gid; }
    else if (gid < 1048576)          { s = s1; d = d1; idx = gid - 786432; }
    else if (gid < 1572864)          { s = s2; d = d2; idx = gid - 1048576; }
    else                             { s = s3; d = d3; idx = gid - 1572864; }
    float4 v = ((const float4*)s)[idx];
    ushort4 o;
    o.x = f2bf(v.x); o.y = f2bf(v.y); o.z = f2bf(v.z); o.w = f2bf(v.w);
    ((ushort4*)d)[idx] = o;
}

// ---------------------------------------------------------------------------
// MFMA GEMM, occupancy-first: C = act(scale * A @ B^T + bias) + residual
//   A: [M,K] bf16 rm (lda), B: [N,K] bf16 rm (ldb), C: bf16/fp32 (ldc)
// Tile BM=128 x BN=256, BK=32, 512 threads = 8 waves (2M x 4N),
// per-wave 64x64 (acc 4x4). LDS: 3 buffers x 24 KB = 72 KB -> 2 blocks/CU
// (16 waves/CU); __launch_bounds__(512,4) pins VGPR <= 128.
// Per K-tile: 8 ds_read_b128 + 3 global_load_lds + 16 MFMA + vmcnt(3) +
// ONE s_barrier. Counted vmcnt: entering tile t, exactly t+1's 3 loads
// outstanding; stage t+2 during t; wait vmcnt(3) at end (tail: 0).
// Swizzle: 16B slot ^= (row>>1)&3 on BOTH stage-source and ds_read
// (verified conflict-free, R1: SQ_LDS_BANK_CONFLICT = 0).
// Requires: M%128==0, N%256==0, K%32==0, K>=96, nwg%8==0.
// ---------------------------------------------------------------------------
__global__ __launch_bounds__(512, 4) void gemm3b(
    const u16* __restrict__ A, const u16* __restrict__ B,
    const float* __restrict__ bias, const float* __restrict__ res,
    void* __restrict__ Cout, int c_fp32,
    int K, int lda, int ldb, int ldc, int ldres, float scale, int act)
{
    __shared__ __align__(16) u16 As[3][128 * 32];   // 3 x 8 KB
    __shared__ __align__(16) u16 Bs[3][256 * 32];   // 3 x 16 KB

    int nt = K >> 5;

    // XCD-aware block swizzle (nwg % 8 == 0 at all call sites)
    int gx  = gridDim.x;
    int nwg = gx * gridDim.y;
    int bid = blockIdx.y * gx + blockIdx.x;
    int cpx = nwg >> 3;
    int swz = (bid & 7) * cpx + (bid >> 3);
    int m0 = (swz / gx) << 7;
    int n0 = (swz % gx) << 8;

    int t = threadIdx.x;
    int w = t >> 6, l = t & 63;
    int wm = w >> 2, wn = w & 3;          // 2M x 4N wave grid
    int lg = l >> 4, lr = l & 15;

    // ---- staging source (pre-swizzled global, linear LDS dest) ----
    int arow = t >> 2, aslot = t & 3;
    int asw  = aslot ^ ((arow >> 1) & 3);
    const u16* Ag  = A + (long long)(m0 + arow) * lda + (asw << 3);
    const u16* Bg0 = B + (long long)(n0 + arow) * ldb + (asw << 3);
    const u16* Bg1 = Bg0 + ((long long)ldb << 7);   // rows 128..255

#define SG(tt, bb) {                                                           \
        GLDS16(Ag  + ((long long)(tt) << 5), &As[bb][w << 9]);                 \
        GLDS16(Bg0 + ((long long)(tt) << 5), &Bs[bb][w << 9]);                 \
        GLDS16(Bg1 + ((long long)(tt) << 5), &Bs[bb][4096 + (w << 9)]); }

    // ---- read-side bases (swizzled slot, lane-constant) ----
    int sx = lg ^ ((lr >> 1) & 3);
    const u16* Asr = &As[0][0] + (wm << 11) + (lr << 5) + (sx << 3);
    const u16* Bsr = &Bs[0][0] + (wn << 11) + (lr << 5) + (sx << 3);

    f32x4 acc[4][4];
#pragma unroll
    for (int i = 0; i < 4; i++)
#pragma unroll
        for (int j = 0; j < 4; j++)
            acc[i][j] = (f32x4){0.f, 0.f, 0.f, 0.f};

    // ---- prologue: stage tiles 0,1; wait tile 0 (3 of tile1 in flight) ----
    SG(0, 0); SG(1, 1);
    asm volatile("s_waitcnt vmcnt(3)" ::: "memory");
    __builtin_amdgcn_s_barrier();
    __builtin_amdgcn_sched_barrier(0);

    int bufR = 0;
    for (int tt = 0; tt < nt; ++tt) {
        const u16* Ab = Asr + (bufR << 12);   // bufR * 4096 u16
        const u16* Bb = Bsr + (bufR << 13);   // bufR * 8192 u16

        bf16x8 av[4], bv[4];
#pragma unroll
        for (int i = 0; i < 4; i++) av[i] = *(const bf16x8*)(Ab + i * 512);
#pragma unroll
        for (int j = 0; j < 4; j++) bv[j] = *(const bf16x8*)(Bb + j * 512);

        if (tt + 2 < nt) {                    // stage t+2 into (bufR+2)%3
            int bw = bufR == 0 ? 2 : bufR - 1;
            SG(tt + 2, bw);
        }

#pragma unroll
        for (int i = 0; i < 4; i++)
#pragma unroll
            for (int j = 0; j < 4; j++)
                acc[i][j] = __builtin_amdgcn_mfma_f32_16x16x32_bf16(av[i], bv[j], acc[i][j], 0, 0, 0);

        if (tt + 2 < nt)      { asm volatile("s_waitcnt vmcnt(3)" ::: "memory"); }
        else if (tt + 1 < nt) { asm volatile("s_waitcnt vmcnt(0)" ::: "memory"); }
        __builtin_amdgcn_s_barrier();
        __builtin_amdgcn_sched_barrier(0);
        bufR = bufR == 2 ? 0 : bufR + 1;
    }
#undef SG

    // ---- epilogue: C/D layout col = lane&15, row = (lane>>4)*4 + r ----
    int rq = lg << 2;
#pragma unroll
    for (int j = 0; j < 4; j++) {
        int col = n0 + (wn << 6) + (j << 4) + lr;
        float bvv = bias ? bias[col] : 0.f;
#pragma unroll
        for (int i = 0; i < 4; i++) {
#pragma unroll
            for (int r = 0; r < 4; r++) {
                int row = m0 + (wm << 6) + (i << 4) + rq + r;
                float v = acc[i][j][r] * scale + bvv;
                if (act) v = 0.5f * v * (1.f + erff(v * 0.70710678118654752f));
                if (res) v += res[(long long)row * ldres + col];
                long long idx = (long long)row * ldc + col;
                if (c_fp32) ((float*)Cout)[idx] = v;
                else        ((u16*)Cout)[idx]  = f2bf(v);
            }
        }
    }
}

// ---------------------------------------------------------------------------
// Fused flash attention (unchanged).
// ---------------------------------------------------------------------------
#define ASCALE 0.08838834764831845f

__global__ __launch_bounds__(256) void attn_kernel(
    const u16* __restrict__ qkv, const u16* __restrict__ vt,
    u16* __restrict__ out)
{
    __shared__ __align__(16) u16 Ks[64 * 128];   // [key][k], slot-swizzled
    __shared__ __align__(16) u16 Vs[128 * 64];   // [d][key], slot-swizzled
    __shared__ __align__(16) u16 Ps[4][32 * 72]; // per-wave P, pad 64->72

    int bh = blockIdx.y; int b = bh >> 3, hd = bh & 7;
    int q0 = blockIdx.x << 7;
    int t = threadIdx.x, w = t >> 6, l = t & 63;
    int lg = l >> 4, lr = l & 15;

    const u16* qp = qkv + ((long long)(b * 1024 + q0 + (w << 5) + lr)) * 3072
                        + hd * 128 + (lg << 3);
    bf16x8 qf[2][4];
#pragma unroll
    for (int rb = 0; rb < 2; rb++)
#pragma unroll
        for (int kf = 0; kf < 4; kf++)
            qf[rb][kf] = *(const bf16x8*)(qp + rb * 16 * 3072 + (kf << 5));

    const u16* kg = qkv + ((long long)(b * 1024)) * 3072 + 1024 + hd * 128;
    const u16* vg = vt + (long long)bh * 131072;
    u16* Pw = &Ps[w][0];

    f32x4 oa[2][8];
#pragma unroll
    for (int rb = 0; rb < 2; rb++)
#pragma unroll
        for (int db = 0; db < 8; db++)
            oa[rb][db] = (f32x4){0.f, 0.f, 0.f, 0.f};
    float m_run[2][4], l_run[2][4];
#pragma unroll
    for (int rb = 0; rb < 2; rb++)
#pragma unroll
        for (int r = 0; r < 4; r++) { m_run[rb][r] = -1e30f; l_run[rb][r] = 0.f; }

    for (int kv0 = 0; kv0 < 1024; kv0 += 64) {
#pragma unroll
        for (int i = 0; i < 4; i++) {
            int ck   = (((w << 2) + i) << 6) + l;
            int krow = ck >> 4;
            int kslot = (ck & 15) ^ (krow & 7);
            GLDS16(kg + (long long)(kv0 + krow) * 3072 + (kslot << 3),
                   Ks + (((w << 2) + i) << 9));
            int vd   = ck >> 3;
            int vslot = (ck & 7) ^ (vd & 7);
            GLDS16(vg + (long long)vd * 1024 + kv0 + (vslot << 3),
                   Vs + (((w << 2) + i) << 9));
        }
        __syncthreads();

        f32x4 s[2][4];
#pragma unroll
        for (int kb = 0; kb < 4; kb++) {
            s[0][kb] = (f32x4){0.f, 0.f, 0.f, 0.f};
            s[1][kb] = (f32x4){0.f, 0.f, 0.f, 0.f};
        }
#pragma unroll
        for (int kf = 0; kf < 4; kf++)
#pragma unroll
            for (int kb = 0; kb < 4; kb++) {
                bf16x8 bk = *(const bf16x8*)
                    &Ks[(((kb << 4) + lr) << 7) + (((((kf << 2) + lg)) ^ (lr & 7)) << 3)];
                s[0][kb] = __builtin_amdgcn_mfma_f32_16x16x32_bf16(qf[0][kf], bk, s[0][kb], 0, 0, 0);
                s[1][kb] = __builtin_amdgcn_mfma_f32_16x16x32_bf16(qf[1][kf], bk, s[1][kb], 0, 0, 0);
            }

#pragma unroll
        for (int rb = 0; rb < 2; rb++) {
            float mx[4], al[4], rs[4];
#pragma unroll
            for (int r = 0; r < 4; r++)
                mx[r] = fmaxf(fmaxf(s[rb][0][r], s[rb][1][r]),
                              fmaxf(s[rb][2][r], s[rb][3][r]));
#pragma unroll
            for (int mask = 1; mask < 16; mask <<= 1)
#pragma unroll
                for (int r = 0; r < 4; r++)
                    mx[r] = fmaxf(mx[r], __shfl_xor(mx[r], mask));
#pragma unroll
            for (int r = 0; r < 4; r++) {
                float mn = fmaxf(m_run[rb][r], mx[r] * ASCALE);
                al[r] = __expf(m_run[rb][r] - mn);
                m_run[rb][r] = mn;
                rs[r] = 0.f;
            }
#pragma unroll
            for (int kb = 0; kb < 4; kb++)
#pragma unroll
                for (int r = 0; r < 4; r++) {
                    float p = __expf(s[rb][kb][r] * ASCALE - m_run[rb][r]);
                    rs[r] += p;
                    Pw[((rb << 4) + (lg << 2) + r) * 72 + (kb << 4) + lr] = f2bf(p);
                }
#pragma unroll
            for (int mask = 1; mask < 16; mask <<= 1)
#pragma unroll
                for (int r = 0; r < 4; r++)
                    rs[r] += __shfl_xor(rs[r], mask);
#pragma unroll
            for (int r = 0; r < 4; r++)
                l_run[rb][r] = l_run[rb][r] * al[r] + rs[r];
#pragma unroll
            for (int db = 0; db < 8; db++)
#pragma unroll
                for (int r = 0; r < 4; r++)
                    oa[rb][db][r] *= al[r];
        }

#pragma unroll
        for (int ks = 0; ks < 2; ks++) {
            bf16x8 pa0 = *(const bf16x8*)&Pw[lr * 72 + (ks << 5) + (lg << 3)];
            bf16x8 pa1 = *(const bf16x8*)&Pw[(16 + lr) * 72 + (ks << 5) + (lg << 3)];
#pragma unroll
            for (int db = 0; db < 8; db++) {
                bf16x8 vf = *(const bf16x8*)
                    &Vs[(((db << 4) + lr) << 6) + ((((ks << 2) + lg) ^ (lr & 7)) << 3)];
                oa[0][db] = __builtin_amdgcn_mfma_f32_16x16x32_bf16(pa0, vf, oa[0][db], 0, 0, 0);
                oa[1][db] = __builtin_amdgcn_mfma_f32_16x16x32_bf16(pa1, vf, oa[1][db], 0, 0, 0);
            }
        }
        __syncthreads();
    }

    long long obase = ((long long)(b * 1024 + q0 + (w << 5)) << 10) + hd * 128;
#pragma unroll
    for (int rb = 0; rb < 2; rb++) {
        float il[4];
#pragma unroll
        for (int r = 0; r < 4; r++) il[r] = 1.f / l_run[rb][r];
#pragma unroll
        for (int db = 0; db < 8; db++)
#pragma unroll
            for (int r = 0; r < 4; r++)
                out[obase + (long long)((rb << 4) + (lg << 2) + r) * 1024
                          + (db << 4) + lr] = f2bf(oa[rb][db][r] * il[r]);
    }
}

// ---------------------------------------------------------------------------
// patch gather
// ---------------------------------------------------------------------------
__global__ __launch_bounds__(256) void patches_kernel(const float* __restrict__ x,
                                                      u16* __restrict__ p)
{
    int gid = blockIdx.x * 256 + threadIdx.x;
    int c = gid & 255, tk = gid >> 8;
    int b = tk >> 10, n = tk & 1023;
    int ph = n >> 5, pw = n & 31;
    int i = c >> 4, j = c & 15;
    p[gid] = f2bf(x[((long long)b << 18) + (long long)(ph * 16 + i) * 512 + pw * 16 + j]);
}

// ---------------------------------------------------------------------------
// positional encoding add
// ---------------------------------------------------------------------------
__global__ __launch_bounds__(256) void posenc_kernel(float* __restrict__ tok)
{
    int gid = blockIdx.x * 256 + threadIdx.x;
    int d = gid & 1023;
    int n = (gid >> 10) & 1023;
    int j = d >> 1;
    float ang = (float)n * exp2f(-13.287712379549449f * (float)j * (1.0f / 256.0f));
    float pe = (d & 1) ? cosf(ang) : sinf(ang);
    tok[gid] += pe;
}

// ---------------------------------------------------------------------------
// LayerNorm over last dim (1024): fp32 in, bf16 out
// ---------------------------------------------------------------------------
__global__ __launch_bounds__(256) void ln_kernel(const float* __restrict__ x,
                                                 const float* __restrict__ g,
                                                 const float* __restrict__ b,
                                                 u16* __restrict__ y)
{
    int row = blockIdx.x, t = threadIdx.x;
    const float* xr = x + (long long)row * 1024;
    float v[4]; float s = 0.f, ss = 0.f;
#pragma unroll
    for (int i = 0; i < 4; i++) { v[i] = xr[i * 256 + t]; s += v[i]; ss += v[i] * v[i]; }
    __shared__ float rs[256], rss[256];
    rs[t] = s; rss[t] = ss; __syncthreads();
    for (int o = 128; o > 0; o >>= 1) {
        if (t < o) { rs[t] += rs[t + o]; rss[t] += rss[t + o]; }
        __syncthreads();
    }
    float mean = rs[0] * (1.f / 1024.f);
    float var  = rss[0] * (1.f / 1024.f) - mean * mean;
    float rstd = rsqrtf(var + 1e-5f);
    u16* yr = y + (long long)row * 1024;
#pragma unroll
    for (int i = 0; i < 4; i++) {
        int d = i * 256 + t;
        yr[d] = f2bf((v[i] - mean) * rstd * g[d] + b[d]);
    }
}

// ---------------------------------------------------------------------------
// V transpose: qkv[token][2048 + head*128 + d] -> vt[bh][d][n]
// ---------------------------------------------------------------------------
__global__ __launch_bounds__(256) void vt_kernel(const u16* __restrict__ qkv,
                                                 u16* __restrict__ vt)
{
    int bh   = blockIdx.x >> 4;
    int tile = blockIdx.x & 15;
    int b = bh >> 3, hd = bh & 7;
    int t = threadIdx.x;
    __shared__ u16 tl[64][130];
    int nk0 = tile * 64;
    int dcol = t & 127, r0 = t >> 7;
    const u16* src = qkv + ((long long)(b * 1024 + nk0)) * 3072 + 2048 + hd * 128 + dcol;
#pragma unroll
    for (int r = 0; r < 32; r++) {
        int nk = r0 + r * 2;
        tl[nk][dcol] = src[(long long)nk * 3072];
    }
    __syncthreads();
    u16* dst = vt + ((long long)bh * 128) * 1024 + nk0;
#pragma unroll
    for (int r = 0; r < 32; r++) {
        int flat = r * 256 + t;
        int d = flat >> 6, nk = flat & 63;
        dst[(long long)d * 1024 + nk] = tl[nk][d];
    }
}

// ---------------------------------------------------------------------------
// reconstruction
// ---------------------------------------------------------------------------
__global__ __launch_bounds__(256) void recon_kernel(const float* __restrict__ tok,
                                                    float* __restrict__ out)
{
    int gid = blockIdx.x * 256 + threadIdx.x;
    int b  = gid >> 20;
    int y  = (gid >> 10) & 1023;
    int xx = gid & 1023;
    int p1 = y & 1,  hh = y >> 1,  a  = hh >> 4, i = hh & 15;
    int p2 = xx & 1, wv = xx >> 1, bb = wv >> 4, j = wv & 15;
    int n = a * 32 + bb;
    int d = ((i * 16 + j) << 2) + (p1 << 1) + p2;
    out[gid] = tok[((long long)(b * 1024 + n) << 10) + d];
}

// ---------------------------------------------------------------------------
extern "C" void kernel_launch(void* const* d_in, const int* in_sizes, int n_in,
                              void* d_out, int out_size, void* d_ws, size_t ws_size,
                              hipStream_t stream)
{
    (void)in_sizes; (void)n_in; (void)out_size; (void)ws_size;
    const float* x      = (const float*)d_in[0];
    const float* conv_w = (const float*)d_in[1];
    const float* conv_b = (const float*)d_in[2];
    const float* ln1_g  = (const float*)d_in[3];
    const float* ln1_b  = (const float*)d_in[4];
    const float* qkv_w  = (const float*)d_in[5];
    const float* qkv_b  = (const float*)d_in[6];
    const float* proj_w = (const float*)d_in[7];
    const float* proj_b = (const float*)d_in[8];
    const float* ln2_g  = (const float*)d_in[9];
    const float* ln2_b  = (const float*)d_in[10];
    const float* fc1_w  = (const float*)d_in[11];
    const float* fc1_b  = (const float*)d_in[12];
    const float* fc2_w  = (const float*)d_in[13];
    const float* fc2_b  = (const float*)d_in[14];

    char* ws = (char*)d_ws;
    float* tokf  = (float*)ws;                         // 33,554,432 B
    u16* h       = (u16*)(ws + 33554432);              // 16,777,216
    u16* qkvb    = (u16*)(ws + 50331648);              // 50,331,648
    u16* vt      = (u16*)(ws + 100663296);             // 16,777,216
    u16* attnout = (u16*)(ws + 117440512);             // 16,777,216
    u16* mid     = (u16*)(ws + 134217728);             // 33,554,432
    u16* patches = (u16*)(ws + 167772160);             //  4,194,304
    u16* convw   = (u16*)(ws + 171966464);             //    524,288
    u16* wqkv    = (u16*)(ws + 172490752);             //  6,291,456
    u16* wproj   = (u16*)(ws + 178782208);             //  2,097,152
    u16* wfc1    = (u16*)(ws + 180879360);             //  4,194,304
    u16* wfc2    = (u16*)(ws + 185073664);             //  4,194,304

    dim3 blk(256);
    dim3 blk512(512);

    // ---- patch embed ----
    patches_kernel<<<dim3(8192), blk, 0, stream>>>(x, patches);
    cvt_kernel<<<dim3(256), blk, 0, stream>>>(conv_w, convw, 65536);
    gemm3b<<<dim3(4, 64), blk512, 0, stream>>>(
        patches, convw, conv_b, (const float*)nullptr, (void*)tokf, 1,
        256, 256, 256, 1024, 0, 1.0f, 0);
    posenc_kernel<<<dim3(32768), blk, 0, stream>>>(tokf);

    // ---- transformer layers ----
    for (int L = 0; L < 12; L++) {
        cvt4_kernel<<<dim3(8192), blk, 0, stream>>>(
            qkv_w + (long long)L * 3145728, proj_w + (long long)L * 1048576,
            fc1_w + (long long)L * 2097152, fc2_w + (long long)L * 2097152,
            wqkv, wproj, wfc1, wfc2);

        ln_kernel<<<dim3(8192), blk, 0, stream>>>(
            tokf, ln1_g + L * 1024, ln1_b + L * 1024, h);

        gemm3b<<<dim3(12, 64), blk512, 0, stream>>>(
            h, wqkv, qkv_b + L * 3072, (const float*)nullptr, (void*)qkvb, 0,
            1024, 1024, 1024, 3072, 0, 1.0f, 0);

        vt_kernel<<<dim3(1024), blk, 0, stream>>>(qkvb, vt);

        attn_kernel<<<dim3(8, 64, 1), blk, 0, stream>>>(qkvb, vt, attnout);

        gemm3b<<<dim3(4, 64), blk512, 0, stream>>>(
            attnout, wproj, proj_b + L * 1024, tokf, (void*)tokf, 1,
            1024, 1024, 1024, 1024, 1024, 1.0f, 0);

        ln_kernel<<<dim3(8192), blk, 0, stream>>>(
            tokf, ln2_g + L * 1024, ln2_b + L * 1024, h);

        gemm3b<<<dim3(8, 64), blk512, 0, stream>>>(
            h, wfc1, fc1_b + L * 2048, (const float*)nullptr, (void*)mid, 0,
            1024, 1024, 1024, 2048, 0, 1.0f, 1);

        gemm3b<<<dim3(4, 64), blk512, 0, stream>>>(
            mid, wfc2, fc2_b + L * 1024, tokf, (void*)tokf, 1,
            2048, 2048, 2048, 1024, 1024, 1.0f, 0);
    }

    // ---- reconstruction ----
    recon_kernel<<<dim3(32768), blk, 0, stream>>>(tokf, (float*)d_out);
}